// Round 6
// baseline (467.772 us; speedup 1.0000x reference)
//
#include <hip/hip_runtime.h>
#include <hip/hip_bf16.h>

#define B_   8
#define TQ_  8
#define TP_  447
#define TC_  1500
#define D_   1280
#define H_   20
#define DH_  64
#define DFF_ 5120
#define M_   64    // B_*TQ_ total rows

// ================= LayerNorm: row-major fp32 in -> ROW-major normed out (coalesced)
__global__ __launch_bounds__(256) void ln_kernel(const float* __restrict__ X,
    const float* __restrict__ g, const float* __restrict__ be, float* __restrict__ out)
{
  __shared__ float redA[4], redB[4];
  const int m = blockIdx.x;
  const int tid = threadIdx.x;
  float v[5];
#pragma unroll
  for (int t = 0; t < 5; ++t) v[t] = X[(size_t)m*D_ + tid + t*256];
  float s = v[0]+v[1]+v[2]+v[3]+v[4];
#pragma unroll
  for (int o = 32; o; o >>= 1) s += __shfl_down(s, o, 64);
  if ((tid & 63) == 0) redA[tid >> 6] = s;
  __syncthreads();
  const float mean = (redA[0]+redA[1]+redA[2]+redA[3]) * (1.0f/D_);
  float q = 0.f;
#pragma unroll
  for (int t = 0; t < 5; ++t) { const float d = v[t]-mean; q += d*d; }
#pragma unroll
  for (int o = 32; o; o >>= 1) q += __shfl_down(q, o, 64);
  if ((tid & 63) == 0) redB[tid >> 6] = q;
  __syncthreads();
  const float rstd = rsqrtf((redB[0]+redB[1]+redB[2]+redB[3]) * (1.0f/D_) + 1e-5f);
#pragma unroll
  for (int t = 0; t < 5; ++t) {
    const int c = tid + t*256;
    out[(size_t)m*D_ + c] = (v[t]-mean)*rstd*g[c] + be[c];
  }
}

// ================= split-K GEMM: P[s][m][n] = sum_k A[m][k]*W[k][n]
// R6: N-tile 64, K-step 32 -> LDS 16KB -> 8 blocks/CU (32 waves, HW cap).
// R5's 48KB tile gave 1 block/CU at 200-block grids = 1 wave/SIMD: zero TLP,
// all LDS/staging latency exposed (GEMMs ran ~10x their compute floor).
// One output column per thread (lane=n), 16 m-accumulators, chunk % 32 == 0.
__global__ __launch_bounds__(256, 8) void gemm_splitk(
    const float* __restrict__ A, int lda,
    const float* __restrict__ Wa, const float* __restrict__ Wb, const float* __restrict__ Wc,
    float* __restrict__ Pa, float* __restrict__ Pb, float* __restrict__ Pc,
    int N, int chunk)
{
  __shared__ float xs[32][64];    // 8 KB, [k][m]
  __shared__ float wsh[32][64];   // 8 KB, [k][n]
  const int z = blockIdx.z;
  const float* W = (z == 0 ? Wa : (z == 1 ? Wb : Wc));
  float* P = (z == 0 ? Pa : (z == 1 ? Pb : Pc));
  const int tid  = threadIdx.x;
  const int lane = tid & 63;
  const int wv   = tid >> 6;
  const int n0   = blockIdx.x*64;
  const int n    = n0 + lane;
  const int k0   = blockIdx.y * chunk;
  const int mrow = tid >> 2;          // 0..63
  const int ks   = (tid & 3) * 8;     // 0,8,16,24
  float acc[16];
#pragma unroll
  for (int r = 0; r < 16; ++r) acc[r] = 0.f;

  for (int kb = 0; kb < chunk; kb += 32) {
    __syncthreads();
    // stage A tile with transpose: A[mrow][k0+kb+ks .. +8] -> xs[k][m]
    {
      const float4* arow = (const float4*)(A + (size_t)mrow*lda + k0 + kb + ks);
#pragma unroll
      for (int i = 0; i < 2; ++i) {
        const float4 av = arow[i];
        const int kk = ks + i*4;
        xs[kk+0][mrow] = av.x;
        xs[kk+1][mrow] = av.y;
        xs[kk+2][mrow] = av.z;
        xs[kk+3][mrow] = av.w;
      }
    }
    // stage W tile: 32 rows x 64 n, 2 float4/thread, 256B-coalesced per row
    {
      const float* Wb0 = W + (size_t)(k0 + kb)*N + n0;
#pragma unroll
      for (int i = 0; i < 2; ++i) {
        const int idx = tid + i*256;            // 0..511 float4 slots
        const int r = idx >> 4, c = (idx & 15)*4;
        *(float4*)&wsh[r][c] = *(const float4*)(Wb0 + (size_t)r*N + c);
      }
    }
    __syncthreads();
#pragma unroll
    for (int kk = 0; kk < 32; ++kk) {
      const float w = wsh[kk][lane];            // stride-1: 2 lanes/bank, free
      const float* xr = &xs[kk][wv*16];         // wave-uniform: broadcast, free
#pragma unroll
      for (int r4 = 0; r4 < 4; ++r4) {
        const float4 xv = *(const float4*)(xr + r4*4);
        acc[r4*4+0] += xv.x*w;
        acc[r4*4+1] += xv.y*w;
        acc[r4*4+2] += xv.z*w;
        acc[r4*4+3] += xv.w*w;
      }
    }
  }
#pragma unroll
  for (int r = 0; r < 16; ++r) {
    const int m = wv*16 + r;
    P[((size_t)blockIdx.y*M_ + m)*N + n] = acc[r];
  }
}

// ================= epilogue: sum split-K partials, +bias, gelu, +residual; row-major outs
template<int S>
__global__ __launch_bounds__(256) void epilogue_kernel(
    const float* __restrict__ P, int N,
    const float* __restrict__ bias,
    const float* __restrict__ res,
    int gelu,
    float* __restrict__ outA, float* __restrict__ outB)
{
  const int idx = blockIdx.x*256 + threadIdx.x;   // < M_*N
  const int m = idx / N;
  const int n = idx - m*N;
  float a = 0.f;
#pragma unroll
  for (int s = 0; s < S; ++s) a += P[((size_t)s*M_ + m)*N + n];
  if (bias) a += bias[n];
  if (gelu) a = 0.5f*a*(1.0f + erff(a*0.70710678118654752f));
  if (res) a += res[idx];
  if (outA) outA[idx] = a;
  if (outB) outB[idx] = a;
}

// ================= fused epilogue (sum partials + bias + residual) + LayerNorm
// both outputs row-major (coalesced)
template<int S>
__global__ __launch_bounds__(256) void epilogue_ln(
    const float* __restrict__ P,
    const float* __restrict__ bias, const float* __restrict__ res,
    const float* __restrict__ g, const float* __restrict__ be,
    float* __restrict__ outRow, float* __restrict__ outLN)
{
  __shared__ float redA[4], redB[4];
  const int m = blockIdx.x;
  const int tid = threadIdx.x;
  float v[5];
#pragma unroll
  for (int t = 0; t < 5; ++t) {
    const int c = tid + t*256;
    float a = 0.f;
#pragma unroll
    for (int s = 0; s < S; ++s) a += P[((size_t)s*M_ + m)*D_ + c];
    a += bias[c] + res[(size_t)m*D_ + c];
    outRow[(size_t)m*D_ + c] = a;
    v[t] = a;
  }
  float s = v[0]+v[1]+v[2]+v[3]+v[4];
#pragma unroll
  for (int o = 32; o; o >>= 1) s += __shfl_down(s, o, 64);
  if ((tid & 63) == 0) redA[tid >> 6] = s;
  __syncthreads();
  const float mean = (redA[0]+redA[1]+redA[2]+redA[3]) * (1.0f/D_);
  float q = 0.f;
#pragma unroll
  for (int t = 0; t < 5; ++t) { const float d = v[t]-mean; q += d*d; }
#pragma unroll
  for (int o = 32; o; o >>= 1) q += __shfl_down(q, o, 64);
  if ((tid & 63) == 0) redB[tid >> 6] = q;
  __syncthreads();
  const float rstd = rsqrtf((redB[0]+redB[1]+redB[2]+redB[3]) * (1.0f/D_) + 1e-5f);
#pragma unroll
  for (int t = 0; t < 5; ++t) {
    const int c = tid + t*256;
    outLN[(size_t)m*D_ + c] = (v[t]-mean)*rstd*g[c] + be[c];
  }
}

// ================= z-batched QKV epilogue: sum 10 partials, per-z bias/outputs
__global__ __launch_bounds__(256) void epilogue_qkv(
    const float* __restrict__ Pq, const float* __restrict__ Pk, const float* __restrict__ Pv,
    const float* __restrict__ bq, const float* __restrict__ bv,
    float* __restrict__ qbuf, float* __restrict__ k1f, float* __restrict__ v1f,
    float* __restrict__ out_k1, float* __restrict__ out_v1)
{
  const int z = blockIdx.z;
  const int idx = blockIdx.x*256 + threadIdx.x;   // < M_*D_
  const float* P = (z == 0 ? Pq : (z == 1 ? Pk : Pv));
  float a = 0.f;
#pragma unroll
  for (int s = 0; s < 10; ++s) a += P[(size_t)s*M_*D_ + idx];
  const int n = idx % D_;
  if (z == 0)      { a += bq[n]; qbuf[idx] = a; }
  else if (z == 1) { k1f[idx] = a; out_k1[idx] = a; }
  else             { a += bv[n]; v1f[idx] = a; out_v1[idx] = a; }
}

// ================= fused attention split: scores + softmax (LDS) + PV partial
// grid (SP, H_, B_), block 256. chunk <= 64.  (unchanged from R4)
#define SCS 10
__global__ __launch_bounds__(256, 7) void attn_fused(
    const float* __restrict__ Q,
    const float* __restrict__ Kc, const float* __restrict__ Kn,
    const float* __restrict__ Vc, const float* __restrict__ Vn,
    const float* __restrict__ mask,
    float* __restrict__ Opart, float* __restrict__ ML,
    int TK, int TPp, int chunk)
{
  __shared__ float sc[64*SCS];      // scores then exp-weights, [jl][SCS]  (2.5KB)
  __shared__ float qs[8*64];        // q rows for this (b,*,h)             (2KB)
  __shared__ float kr[64*68];       // K tile [row][68] (phase 0/1) == red (phase 3) (17KB)
  const int tid = threadIdx.x;
  const int sp = blockIdx.x, h = blockIdx.y, b = blockIdx.z;
  const int SP = gridDim.x;
  const int j0 = sp * chunk;
  const int cnt = min(chunk, TK - j0);
  const int bh = b*H_ + h;

  // stage q: 512 floats (coalesced, lane=d)
  {
    const int i = tid >> 6, d = tid & 63;
    qs[tid]       = Q[((size_t)(b*TQ_ + i    ))*D_ + h*DH_ + d];
    qs[tid + 256] = Q[((size_t)(b*TQ_ + i + 4))*D_ + h*DH_ + d];
  }
  // stage K tile: cnt rows x 64 dims, coalesced float4 (16 lanes per row)
  for (int u = tid; u < cnt*16; u += 256) {
    const int r = u >> 4, c = u & 15;
    const int j = j0 + r;
    const float* kg = (j < TPp)
      ? Kc + ((size_t)b*TPp + j)*D_ + h*DH_
      : Kn + ((size_t)(b*TQ_ + (j - TPp)))*D_ + h*DH_;
    *(float4*)&kr[r*68 + c*4] = *(const float4*)(kg + c*4);
  }
  __syncthreads();

  // ---- phase 1: scores; 4 threads per key row (16 dims each), shfl_xor combine ----
  {
    const int jl = tid >> 2, qt = tid & 3;
    if (jl < cnt) {
      const float* krow = &kr[jl*68 + qt*16];
      const float4 k0 = *(const float4*)(krow);
      const float4 k1 = *(const float4*)(krow + 4);
      const float4 k2 = *(const float4*)(krow + 8);
      const float4 k3 = *(const float4*)(krow + 12);
      float acc[8];
#pragma unroll
      for (int i = 0; i < 8; ++i) {
        const float* qp = &qs[i*64 + qt*16];
        const float4 q0 = *(const float4*)(qp);
        const float4 q1 = *(const float4*)(qp + 4);
        const float4 q2 = *(const float4*)(qp + 8);
        const float4 q3 = *(const float4*)(qp + 12);
        acc[i] = q0.x*k0.x + q0.y*k0.y + q0.z*k0.z + q0.w*k0.w
               + q1.x*k1.x + q1.y*k1.y + q1.z*k1.z + q1.w*k1.w
               + q2.x*k2.x + q2.y*k2.y + q2.z*k2.z + q2.w*k2.w
               + q3.x*k3.x + q3.y*k3.y + q3.z*k3.z + q3.w*k3.w;
      }
#pragma unroll
      for (int i = 0; i < 8; ++i) {
        acc[i] += __shfl_xor(acc[i], 1, 64);
        acc[i] += __shfl_xor(acc[i], 2, 64);
      }
      if (qt == 0) {
        const int j = j0 + jl;
#pragma unroll
        for (int i = 0; i < 8; ++i) {
          float vv = acc[i]*0.125f;       // (dh^-0.25)^2 on the q.k product
          if (mask) vv += mask[(size_t)i*TK + j];
          sc[jl*SCS + i] = vv;
        }
      }
    }
  }
  __syncthreads();

  // ---- phase 2: per-split softmax, exp in place; 8 row-groups x 32 lanes ----
  {
    const int g = tid >> 5, l = tid & 31;
    float mx = -3.0e38f;
    for (int jl = l; jl < cnt; jl += 32) mx = fmaxf(mx, sc[jl*SCS + g]);
#pragma unroll
    for (int o = 16; o; o >>= 1) mx = fmaxf(mx, __shfl_down(mx, o, 32));
    mx = __shfl(mx, 0, 32);
    float sum = 0.f;
    for (int jl = l; jl < cnt; jl += 32) {
      const float e = __expf(sc[jl*SCS + g] - mx);
      sc[jl*SCS + g] = e;
      sum += e;
    }
#pragma unroll
    for (int o = 16; o; o >>= 1) sum += __shfl_down(sum, o, 32);
    if (l == 0) {
      ML[((size_t)bh*SP + sp)*16 + g]     = mx;
      ML[((size_t)bh*SP + sp)*16 + 8 + g] = sum;
    }
  }
  __syncthreads();

  // ---- phase 3: PV. Waves interleave over j (V read ONCE per block, 256B/instr);
  //      lane = d; all 8 q-rows accumulated per lane; LDS-broadcast weights ----
  {
    const int wv = tid >> 6;
    const int d  = tid & 63;
    float acc[8] = {0.f,0.f,0.f,0.f,0.f,0.f,0.f,0.f};
#pragma unroll 4
    for (int jl = wv; jl < cnt; jl += 4) {
      const int j = j0 + jl;
      const float vv = (j < TPp)
        ? Vc[((size_t)b*TPp + j)*D_ + h*DH_ + d]
        : Vn[((size_t)(b*TQ_ + (j - TPp)))*D_ + h*DH_ + d];
      const float2 p0 = *(const float2*)&sc[jl*SCS + 0];   // broadcast, conflict-free
      const float2 p1 = *(const float2*)&sc[jl*SCS + 2];
      const float2 p2 = *(const float2*)&sc[jl*SCS + 4];
      const float2 p3 = *(const float2*)&sc[jl*SCS + 6];
      acc[0] += p0.x*vv; acc[1] += p0.y*vv;
      acc[2] += p1.x*vv; acc[3] += p1.y*vv;
      acc[4] += p2.x*vv; acc[5] += p2.y*vv;
      acc[6] += p3.x*vv; acc[7] += p3.y*vv;
    }
#pragma unroll
    for (int i = 0; i < 8; ++i) kr[(wv*8 + i)*64 + d] = acc[i];
  }
  __syncthreads();
  {
#pragma unroll
    for (int t = 0; t < 2; ++t) {
      const int o = tid + t*256;        // < 512
      const int i = o >> 6, d = o & 63;
      const float r = kr[(0*8 + i)*64 + d] + kr[(1*8 + i)*64 + d]
                    + kr[(2*8 + i)*64 + d] + kr[(3*8 + i)*64 + d];
      Opart[(((size_t)bh*SP + sp)*8 + i)*64 + d] = r;
    }
  }
}

// ================= merge PV partials with split-softmax weights; ROW-major out (coalesced)
__global__ __launch_bounds__(256) void attn_pv_combine(
    const float* __restrict__ Opart, const float* __restrict__ ML,
    float* __restrict__ out, int SP)
{
  const int tid = threadIdx.x;
  const int h = blockIdx.x, b = blockIdx.y;
  const int bh = b*H_ + h;
  const int wv = tid >> 6, d = tid & 63;
  const int i0 = wv*2, i1 = i0 + 1;
  float M0 = -3.0e38f, M1 = -3.0e38f;
  for (int s = 0; s < SP; ++s) {
    M0 = fmaxf(M0, ML[((size_t)bh*SP + s)*16 + i0]);
    M1 = fmaxf(M1, ML[((size_t)bh*SP + s)*16 + i1]);
  }
  float L0 = 0.f, L1 = 0.f, o0 = 0.f, o1 = 0.f;
  for (int s = 0; s < SP; ++s) {
    const float w0 = __expf(ML[((size_t)bh*SP + s)*16 + i0] - M0);
    const float w1 = __expf(ML[((size_t)bh*SP + s)*16 + i1] - M1);
    L0 += w0 * ML[((size_t)bh*SP + s)*16 + 8 + i0];
    L1 += w1 * ML[((size_t)bh*SP + s)*16 + 8 + i1];
    o0 += w0 * Opart[(((size_t)bh*SP + s)*8 + i0)*64 + d];
    o1 += w1 * Opart[(((size_t)bh*SP + s)*8 + i1)*64 + d];
  }
  out[((size_t)(b*TQ_ + i0))*D_ + h*DH_ + d] = o0 / L0;
  out[((size_t)(b*TQ_ + i1))*D_ + h*DH_ + d] = o1 / L1;
}

extern "C" void kernel_launch(void* const* d_in, const int* in_sizes, int n_in,
                              void* d_out, int out_size, void* d_ws, size_t ws_size,
                              hipStream_t stream)
{
  (void)in_sizes; (void)n_in; (void)out_size; (void)ws_size;
  const float* x    = (const float*)d_in[0];
  const float* skc  = (const float*)d_in[1];
  const float* svc  = (const float*)d_in[2];
  const float* ck   = (const float*)d_in[3];
  const float* cv   = (const float*)d_in[4];
  const float* msk  = (const float*)d_in[5];
  const float* wq   = (const float*)d_in[6];
  const float* bq   = (const float*)d_in[7];
  const float* wk   = (const float*)d_in[8];
  const float* wvv  = (const float*)d_in[9];
  const float* bv   = (const float*)d_in[10];
  const float* wo   = (const float*)d_in[11];
  const float* bo   = (const float*)d_in[12];
  const float* cwq  = (const float*)d_in[13];
  const float* cbq  = (const float*)d_in[14];
  const float* cwo  = (const float*)d_in[15];
  const float* cbo  = (const float*)d_in[16];
  const float* ln1w = (const float*)d_in[17];
  const float* ln1b = (const float*)d_in[18];
  const float* ln2w = (const float*)d_in[19];
  const float* ln2b = (const float*)d_in[20];
  const float* ln3w = (const float*)d_in[21];
  const float* ln3b = (const float*)d_in[22];
  const float* w1   = (const float*)d_in[23];
  const float* b1   = (const float*)d_in[24];
  const float* w2   = (const float*)d_in[25];
  const float* b2   = (const float*)d_in[26];
  // d_in[27] = offset (int) — fixed at TP_ here.

  float* out_x  = (float*)d_out;
  float* out_k1 = out_x + 81920;
  float* out_v1 = out_x + 163840;

  float* ws = (float*)d_ws;
  float* xl   = ws + 0;               // [64][1280] row-major LN output, reused 3x
  float* qbuf = ws + 81920;           // q / qc row-major [64][1280]
  float* k1f  = ws + 163840;
  float* v1f  = ws + 245760;
  float* x2   = ws + 327680;
  float* x3   = ws + 409600;
  float* attO = ws + 491520;          // attn out row-major, reused 2x
  float* hbuf = ws + 573440;          // [64][5120] row-major
  float* Pg   = ws + 901120;          // split-K partials / attention Opart (3.28M floats)
  float* Pq   = Pg;
  float* Pk   = Pg + 819200;
  float* Pv   = Pg + 1638400;
  float* MLS  = ws + 4177920;         // 160*8*16
  float* MLC  = ws + 4218880;         // 160*24*16

  const dim3 blk(256);

  // --- self-attention ---
  ln_kernel<<<dim3(64), blk, 0, stream>>>(x, ln1w, ln1b, xl);
  // QKV: N-tile 64 -> grid (20,10,3) = 600 blocks, chunk 128 (4 K-steps)
  gemm_splitk<<<dim3(20,10,3), blk, 0, stream>>>(xl, D_, wq, wk, wvv, Pq, Pk, Pv, 1280, 128);
  epilogue_qkv<<<dim3(320,1,3), blk, 0, stream>>>(Pq, Pk, Pv, bq, bv, qbuf, k1f, v1f, out_k1, out_v1);
  // SP=8, chunk=57 (8*57=456 >= 455)
  attn_fused<<<dim3(8,20,8), blk, 0, stream>>>(qbuf, skc, k1f, svc, v1f, msk, Pg, MLS, 455, 447, 57);
  attn_pv_combine<<<dim3(20,8), blk, 0, stream>>>(Pg, MLS, attO, 8);
  // wo: 40-way split-K (chunk 32) -> 800 blocks
  gemm_splitk<<<dim3(20,40,1), blk, 0, stream>>>(attO, D_, wo, wo, wo, Pq, Pq, Pq, 1280, 32);
  epilogue_ln<40><<<dim3(64), blk, 0, stream>>>(Pq, bo, x, ln2w, ln2b, x2, xl);

  // --- cross-attention ---
  gemm_splitk<<<dim3(20,40,1), blk, 0, stream>>>(xl, D_, cwq, cwq, cwq, Pq, Pq, Pq, 1280, 32);
  epilogue_kernel<40><<<dim3(320), blk, 0, stream>>>(Pq, 1280, cbq, nullptr, 0, qbuf, nullptr);
  // SP=24, chunk=64 (23*64=1472, last split 28 rows)
  attn_fused<<<dim3(24,20,8), blk, 0, stream>>>(qbuf, ck, nullptr, cv, nullptr, nullptr, Pg, MLC, 1500, 1500, 64);
  attn_pv_combine<<<dim3(20,8), blk, 0, stream>>>(Pg, MLC, attO, 24);
  gemm_splitk<<<dim3(20,40,1), blk, 0, stream>>>(attO, D_, cwo, cwo, cwo, Pq, Pq, Pq, 1280, 32);
  epilogue_ln<40><<<dim3(64), blk, 0, stream>>>(Pq, cbo, x2, ln3w, ln3b, x3, xl);

  // --- MLP ---
  // w1: N=5120 -> grid (80,10) = 800 blocks, chunk 128; partials 10*64*5120 fit Pg
  gemm_splitk<<<dim3(80,10,1), blk, 0, stream>>>(xl, D_, w1, w1, w1, Pg, Pg, Pg, 5120, 128);
  epilogue_kernel<10><<<dim3(1280), blk, 0, stream>>>(Pg, 5120, b1, nullptr, 1, hbuf, nullptr);
  // w2: K=5120 -> 40 splits of chunk 128 -> grid (20,40) = 800 blocks
  gemm_splitk<<<dim3(20,40,1), blk, 0, stream>>>(hbuf, DFF_, w2, w2, w2, Pg, Pg, Pg, 1280, 128);
  epilogue_kernel<40><<<dim3(320), blk, 0, stream>>>(Pg, 1280, b2, x3, 0, out_x, nullptr);
}